// Round 1
// baseline (174.193 us; speedup 1.0000x reference)
//
#include <hip/hip_runtime.h>

#define NBLK 2048
#define NTHR 256

__global__ __launch_bounds__(NTHR) void edge_loss_partial(
    const int*   __restrict__ node_classes,
    const float* __restrict__ edge_scores,
    const int*   __restrict__ edge_src,
    const int*   __restrict__ edge_dst,
    const float* __restrict__ adj,
    float*       __restrict__ partial,
    int n_edges)
{
    __shared__ unsigned s_mask[16];
    const int tid = threadIdx.x;

    // Build 12 row bitmasks of the 12x12 adjacency in LDS.
    if (tid < 12) {
        unsigned m = 0u;
        #pragma unroll
        for (int j = 0; j < 12; ++j)
            if (adj[tid * 12 + j] > 0.5f) m |= (1u << j);
        s_mask[tid] = m;
    }
    __syncthreads();

    const int gtid   = blockIdx.x * NTHR + tid;
    const int stride = gridDim.x * NTHR;
    const int ngrp   = n_edges >> 2;   // groups of 4 edges (float4/int4)

    float acc = 0.0f;

    for (int g = gtid; g < ngrp; g += stride) {
        const int4   s_idx = ((const int4*)  edge_src   )[g];
        const int4   d_idx = ((const int4*)  edge_dst   )[g];
        const float4 sc    = ((const float4*)edge_scores)[g];

        int sc0 = node_classes[s_idx.x];
        int sc1 = node_classes[s_idx.y];
        int sc2 = node_classes[s_idx.z];
        int sc3 = node_classes[s_idx.w];
        int dc0 = node_classes[d_idx.x];
        int dc1 = node_classes[d_idx.y];
        int dc2 = node_classes[d_idx.z];
        int dc3 = node_classes[d_idx.w];

        float y0 = (float)((s_mask[sc0] >> dc0) & 1u);
        float y1 = (float)((s_mask[sc1] >> dc1) & 1u);
        float y2 = (float)((s_mask[sc2] >> dc2) & 1u);
        float y3 = (float)((s_mask[sc3] >> dc3) & 1u);

        float s0 = sc.x, s1 = sc.y, s2 = sc.z, s3 = sc.w;

        acc += fmaxf(s0, 0.0f) - s0 * y0 + log1pf(__expf(-fabsf(s0)));
        acc += fmaxf(s1, 0.0f) - s1 * y1 + log1pf(__expf(-fabsf(s1)));
        acc += fmaxf(s2, 0.0f) - s2 * y2 + log1pf(__expf(-fabsf(s2)));
        acc += fmaxf(s3, 0.0f) - s3 * y3 + log1pf(__expf(-fabsf(s3)));
    }

    // Scalar tail (n_edges not divisible by 4).
    for (int e = (ngrp << 2) + gtid; e < n_edges; e += stride) {
        int scl = node_classes[edge_src[e]];
        int dcl = node_classes[edge_dst[e]];
        float y = (float)((s_mask[scl] >> dcl) & 1u);
        float s = edge_scores[e];
        acc += fmaxf(s, 0.0f) - s * y + log1pf(__expf(-fabsf(s)));
    }

    // Wave (64-lane) shuffle reduction.
    #pragma unroll
    for (int off = 32; off > 0; off >>= 1)
        acc += __shfl_down(acc, off, 64);

    // Cross-wave reduction via LDS (NTHR/64 = 4 waves).
    __shared__ float s_wsum[NTHR / 64];
    const int wave = tid >> 6;
    const int lane = tid & 63;
    if (lane == 0) s_wsum[wave] = acc;
    __syncthreads();

    if (tid == 0) {
        float b = 0.0f;
        #pragma unroll
        for (int w = 0; w < NTHR / 64; ++w) b += s_wsum[w];
        partial[blockIdx.x] = b;   // written unconditionally every launch
    }
}

__global__ __launch_bounds__(256) void final_reduce(
    const float* __restrict__ partial,
    float*       __restrict__ out,
    int nblk, float inv_n)
{
    const int tid = threadIdx.x;
    double acc = 0.0;
    for (int i = tid; i < nblk; i += 256) acc += (double)partial[i];

    #pragma unroll
    for (int off = 32; off > 0; off >>= 1)
        acc += __shfl_down(acc, off, 64);

    __shared__ double s_wsum[4];
    const int wave = tid >> 6;
    const int lane = tid & 63;
    if (lane == 0) s_wsum[wave] = acc;
    __syncthreads();

    if (tid == 0) {
        double t = s_wsum[0] + s_wsum[1] + s_wsum[2] + s_wsum[3];
        out[0] = (float)(t * (double)inv_n);
    }
}

extern "C" void kernel_launch(void* const* d_in, const int* in_sizes, int n_in,
                              void* d_out, int out_size, void* d_ws, size_t ws_size,
                              hipStream_t stream) {
    const int*   node_classes = (const int*)  d_in[0];
    const float* edge_scores  = (const float*)d_in[1];
    const int*   edge_indices = (const int*)  d_in[2];
    const float* adj          = (const float*)d_in[3];

    const int n_edges = in_sizes[1];            // edge_scores is (N_EDGES, 1)
    const int* edge_src = edge_indices;
    const int* edge_dst = edge_indices + n_edges;

    float* partial = (float*)d_ws;
    float* out     = (float*)d_out;

    edge_loss_partial<<<NBLK, NTHR, 0, stream>>>(
        node_classes, edge_scores, edge_src, edge_dst, adj, partial, n_edges);

    final_reduce<<<1, 256, 0, stream>>>(partial, out, NBLK, 1.0f / (float)n_edges);
}

// Round 2
// 145.906 us; speedup vs baseline: 1.1939x; 1.1939x over previous
//
#include <hip/hip_runtime.h>

#define EDGE_BLOCKS  768
#define EDGE_THREADS 256

// ws layout (bytes):
//   [0, 24)        : 3 x u64 adjacency pair-masks (bit b = src*12+dst)
//   [256, 256+EDGE_BLOCKS*4) : per-block float partials
//   [8192, 8192+4*n_words)   : packed 4-bit node-class table
#define WS_MASK_OFF    0
#define WS_PART_OFF    256
#define WS_PACK_OFF    8192

// ---------- kernel A: pack node classes to nibbles + build pair masks ----------
__global__ void pack_classes(const int* __restrict__ node_classes,
                             const float* __restrict__ adj,
                             unsigned* __restrict__ packed,
                             unsigned long long* __restrict__ masks,
                             int n_nodes, int n_words)
{
    int w = blockIdx.x * blockDim.x + threadIdx.x;
    if (w < n_words) {
        unsigned v = 0;
        int base = w << 3;
        #pragma unroll
        for (int j = 0; j < 8; ++j) {
            int n = base + j;
            unsigned c = (n < n_nodes) ? (unsigned)node_classes[n] : 0u;
            v |= (c & 0xFu) << (4 * j);
        }
        packed[w] = v;
    }
    if (w == 0) {
        unsigned long long m0 = 0, m1 = 0, m2 = 0;
        for (int b = 0; b < 144; ++b) {
            if (adj[b] > 0.5f) {
                if (b < 64)       m0 |= 1ull << b;
                else if (b < 128) m1 |= 1ull << (b - 64);
                else              m2 |= 1ull << (b - 128);
            }
        }
        masks[0] = m0; masks[1] = m1; masks[2] = m2;
    }
}

// ---------- helpers ----------
__device__ __forceinline__ int cls_of(const unsigned* __restrict__ s_packed, int n) {
    unsigned w = s_packed[n >> 3];
    return (int)((w >> ((n & 7) << 2)) & 0xFu);
}

__device__ __forceinline__ float y_of(int sc, int dc,
                                      unsigned long long m0,
                                      unsigned long long m1,
                                      unsigned long long m2) {
    int b = sc * 12 + dc;
    unsigned long long p = (b < 64) ? m0 : ((b < 128) ? m1 : m2);
    return (float)((unsigned)(p >> (b & 63)) & 1u);
}

__device__ __forceinline__ float bce_term(float s, float y) {
    return fmaxf(s, 0.0f) - s * y + log1pf(__expf(-fabsf(s)));
}

// ---------- kernel B: edge loss with LDS-resident class table ----------
__global__ __launch_bounds__(EDGE_THREADS) void edge_loss_lds(
    const unsigned* __restrict__ packed_g,
    const unsigned long long* __restrict__ masks_g,
    const float* __restrict__ edge_scores,
    const int*   __restrict__ edge_src,
    const int*   __restrict__ edge_dst,
    float*       __restrict__ partial,
    int n_edges, int n_words)
{
    __shared__ unsigned s_packed[12512];   // 50 048 B
    const int tid = threadIdx.x;

    // Stage packed table into LDS, 16 B per lane (ds_write_b128, conflict-free).
    {
        int nv = n_words >> 2;
        const uint4* p4 = (const uint4*)packed_g;
        for (int i = tid; i < nv; i += EDGE_THREADS) {
            uint4 v = p4[i];
            s_packed[4*i+0] = v.x; s_packed[4*i+1] = v.y;
            s_packed[4*i+2] = v.z; s_packed[4*i+3] = v.w;
        }
        for (int i = (nv << 2) + tid; i < n_words; i += EDGE_THREADS)
            s_packed[i] = packed_g[i];
    }
    const unsigned long long m0 = masks_g[0];
    const unsigned long long m1 = masks_g[1];
    const unsigned long long m2 = masks_g[2];
    __syncthreads();

    const int gtid   = blockIdx.x * EDGE_THREADS + tid;
    const int stride = gridDim.x * EDGE_THREADS;
    const int ngrp   = n_edges >> 2;

    float acc = 0.0f;

    for (int g = gtid; g < ngrp; g += stride) {
        const int4   si = ((const int4*)  edge_src   )[g];
        const int4   di = ((const int4*)  edge_dst   )[g];
        const float4 sc = ((const float4*)edge_scores)[g];

        int a0 = cls_of(s_packed, si.x), a1 = cls_of(s_packed, si.y);
        int a2 = cls_of(s_packed, si.z), a3 = cls_of(s_packed, si.w);
        int b0 = cls_of(s_packed, di.x), b1 = cls_of(s_packed, di.y);
        int b2 = cls_of(s_packed, di.z), b3 = cls_of(s_packed, di.w);

        acc += bce_term(sc.x, y_of(a0, b0, m0, m1, m2));
        acc += bce_term(sc.y, y_of(a1, b1, m0, m1, m2));
        acc += bce_term(sc.z, y_of(a2, b2, m0, m1, m2));
        acc += bce_term(sc.w, y_of(a3, b3, m0, m1, m2));
    }

    for (int e = (ngrp << 2) + gtid; e < n_edges; e += stride) {
        int a = cls_of(s_packed, edge_src[e]);
        int b = cls_of(s_packed, edge_dst[e]);
        acc += bce_term(edge_scores[e], y_of(a, b, m0, m1, m2));
    }

    #pragma unroll
    for (int off = 32; off > 0; off >>= 1)
        acc += __shfl_down(acc, off, 64);

    __shared__ float s_wsum[EDGE_THREADS / 64];
    const int wave = tid >> 6;
    const int lane = tid & 63;
    if (lane == 0) s_wsum[wave] = acc;
    __syncthreads();

    if (tid == 0) {
        float b = 0.0f;
        #pragma unroll
        for (int w = 0; w < EDGE_THREADS / 64; ++w) b += s_wsum[w];
        partial[blockIdx.x] = b;
    }
}

// ---------- fallback (round-1 structure) if ws_size is too small ----------
__global__ __launch_bounds__(EDGE_THREADS) void edge_loss_fallback(
    const int*   __restrict__ node_classes,
    const float* __restrict__ edge_scores,
    const int*   __restrict__ edge_src,
    const int*   __restrict__ edge_dst,
    const float* __restrict__ adj,
    float*       __restrict__ partial,
    int n_edges)
{
    __shared__ unsigned s_mask[16];
    const int tid = threadIdx.x;
    if (tid < 12) {
        unsigned m = 0u;
        for (int j = 0; j < 12; ++j)
            if (adj[tid * 12 + j] > 0.5f) m |= (1u << j);
        s_mask[tid] = m;
    }
    __syncthreads();

    const int gtid   = blockIdx.x * EDGE_THREADS + tid;
    const int stride = gridDim.x * EDGE_THREADS;
    float acc = 0.0f;
    for (int e = gtid; e < n_edges; e += stride) {
        int a = node_classes[edge_src[e]];
        int b = node_classes[edge_dst[e]];
        float y = (float)((s_mask[a] >> b) & 1u);
        acc += bce_term(edge_scores[e], y);
    }
    #pragma unroll
    for (int off = 32; off > 0; off >>= 1)
        acc += __shfl_down(acc, off, 64);
    __shared__ float s_wsum[EDGE_THREADS / 64];
    const int wave = tid >> 6, lane = tid & 63;
    if (lane == 0) s_wsum[wave] = acc;
    __syncthreads();
    if (tid == 0) {
        float b = 0.0f;
        for (int w = 0; w < EDGE_THREADS / 64; ++w) b += s_wsum[w];
        partial[blockIdx.x] = b;
    }
}

__global__ __launch_bounds__(256) void final_reduce(
    const float* __restrict__ partial,
    float*       __restrict__ out,
    int nblk, float inv_n)
{
    const int tid = threadIdx.x;
    double acc = 0.0;
    for (int i = tid; i < nblk; i += 256) acc += (double)partial[i];
    #pragma unroll
    for (int off = 32; off > 0; off >>= 1)
        acc += __shfl_down(acc, off, 64);
    __shared__ double s_wsum[4];
    const int wave = tid >> 6, lane = tid & 63;
    if (lane == 0) s_wsum[wave] = acc;
    __syncthreads();
    if (tid == 0) {
        double t = s_wsum[0] + s_wsum[1] + s_wsum[2] + s_wsum[3];
        out[0] = (float)(t * (double)inv_n);
    }
}

extern "C" void kernel_launch(void* const* d_in, const int* in_sizes, int n_in,
                              void* d_out, int out_size, void* d_ws, size_t ws_size,
                              hipStream_t stream) {
    const int*   node_classes = (const int*)  d_in[0];
    const float* edge_scores  = (const float*)d_in[1];
    const int*   edge_indices = (const int*)  d_in[2];
    const float* adj          = (const float*)d_in[3];

    const int n_nodes = in_sizes[0];
    const int n_edges = in_sizes[1];
    const int n_words = (n_nodes + 7) >> 3;

    const int* edge_src = edge_indices;
    const int* edge_dst = edge_indices + n_edges;

    char* ws = (char*)d_ws;
    unsigned long long* masks  = (unsigned long long*)(ws + WS_MASK_OFF);
    float*              partial = (float*)             (ws + WS_PART_OFF);
    unsigned*           packed  = (unsigned*)          (ws + WS_PACK_OFF);
    float* out = (float*)d_out;

    const size_t needed = (size_t)WS_PACK_OFF + (size_t)n_words * 4u;

    if (ws_size >= needed && n_nodes < (12512 * 8)) {
        int pack_blocks = (n_words + 255) / 256;
        pack_classes<<<pack_blocks, 256, 0, stream>>>(
            node_classes, adj, packed, masks, n_nodes, n_words);
        edge_loss_lds<<<EDGE_BLOCKS, EDGE_THREADS, 0, stream>>>(
            packed, masks, edge_scores, edge_src, edge_dst, partial,
            n_edges, n_words);
    } else {
        edge_loss_fallback<<<EDGE_BLOCKS, EDGE_THREADS, 0, stream>>>(
            node_classes, edge_scores, edge_src, edge_dst, adj, partial, n_edges);
    }

    final_reduce<<<1, 256, 0, stream>>>(partial, out, EDGE_BLOCKS,
                                        1.0f / (float)n_edges);
}

// Round 3
// 121.326 us; speedup vs baseline: 1.4357x; 1.2026x over previous
//
#include <hip/hip_runtime.h>

#define EDGE_BLOCKS  512
#define EDGE_THREADS 1024
#define PACK_WORDS_MAX 12512   // 50,048 B LDS table -> supports n_nodes <= 100,096

// ws layout (bytes):
//   [0, 24)                     : 3 x u64 (unused by edge kernel now, kept for pack)
//   [256, 256+EDGE_BLOCKS*4)    : per-block float partials
//   [8192, 8192+4*n_words)      : packed 4-bit node-class table
#define WS_MASK_OFF    0
#define WS_PART_OFF    256
#define WS_PACK_OFF    8192

// ---------- kernel A: pack node classes to nibbles ----------
__global__ void pack_classes(const int* __restrict__ node_classes,
                             unsigned* __restrict__ packed,
                             int n_nodes, int n_words)
{
    int w = blockIdx.x * blockDim.x + threadIdx.x;
    if (w < n_words) {
        unsigned v = 0;
        int base = w << 3;
        #pragma unroll
        for (int j = 0; j < 8; ++j) {
            int n = base + j;
            unsigned c = (n < n_nodes) ? (unsigned)node_classes[n] : 0u;
            v |= (c & 0xFu) << (4 * j);
        }
        packed[w] = v;
    }
}

// ---------- fast BCE pieces ----------
#define LOG2E 1.44269504088896f
#define LN2   0.69314718055995f

// ---------- kernel B: edge loss, LDS class table, high occupancy ----------
__global__ __launch_bounds__(EDGE_THREADS, 8) void edge_loss_lds(
    const unsigned* __restrict__ packed_g,
    const float* __restrict__ edge_scores,
    const int*   __restrict__ edge_src,
    const int*   __restrict__ edge_dst,
    const float* __restrict__ adj,
    float*       __restrict__ partial,
    int n_edges, int n_words)
{
    __shared__ unsigned s_packed[PACK_WORDS_MAX]; // 50,048 B
    __shared__ unsigned s_mask[16];               // 12-bit row masks (broadcast reads)
    __shared__ float    s_wsum[EDGE_THREADS / 64];

    const int tid = threadIdx.x;

    if (tid < 16) {
        unsigned m = 0u;
        if (tid < 12) {
            #pragma unroll
            for (int j = 0; j < 12; ++j)
                if (adj[tid * 12 + j] > 0.5f) m |= (1u << j);
        }
        s_mask[tid] = m;
    }
    // Stage packed table, 16B chunks (coalesced, conflict-free writes).
    {
        int nv = n_words >> 2;
        const uint4* p4 = (const uint4*)packed_g;
        for (int i = tid; i < nv; i += EDGE_THREADS) {
            uint4 v = p4[i];
            s_packed[4*i+0] = v.x; s_packed[4*i+1] = v.y;
            s_packed[4*i+2] = v.z; s_packed[4*i+3] = v.w;
        }
        for (int i = (nv << 2) + tid; i < n_words; i += EDGE_THREADS)
            s_packed[i] = packed_g[i];
    }
    __syncthreads();

    const int gtid   = blockIdx.x * EDGE_THREADS + tid;
    const int stride = gridDim.x * EDGE_THREADS;
    const int ngrp   = n_edges >> 2;

    float acc = 0.0f;

    for (int g = gtid; g < ngrp; g += stride) {
        const int4   si = ((const int4*)  edge_src   )[g];
        const int4   di = ((const int4*)  edge_dst   )[g];
        const float4 sc = ((const float4*)edge_scores)[g];

        // nibble gathers (random LDS)
        unsigned wa0 = s_packed[si.x >> 3], wa1 = s_packed[si.y >> 3];
        unsigned wa2 = s_packed[si.z >> 3], wa3 = s_packed[si.w >> 3];
        unsigned wb0 = s_packed[di.x >> 3], wb1 = s_packed[di.y >> 3];
        unsigned wb2 = s_packed[di.z >> 3], wb3 = s_packed[di.w >> 3];

        int a0 = (wa0 >> ((si.x & 7) << 2)) & 0xF;
        int a1 = (wa1 >> ((si.y & 7) << 2)) & 0xF;
        int a2 = (wa2 >> ((si.z & 7) << 2)) & 0xF;
        int a3 = (wa3 >> ((si.w & 7) << 2)) & 0xF;
        int b0 = (wb0 >> ((di.x & 7) << 2)) & 0xF;
        int b1 = (wb1 >> ((di.y & 7) << 2)) & 0xF;
        int b2 = (wb2 >> ((di.z & 7) << 2)) & 0xF;
        int b3 = (wb3 >> ((di.w & 7) << 2)) & 0xF;

        // broadcast mask reads (12 distinct words -> 12 distinct banks, no conflict)
        unsigned y0 = (s_mask[a0] >> b0) & 1u;
        unsigned y1 = (s_mask[a1] >> b1) & 1u;
        unsigned y2 = (s_mask[a2] >> b2) & 1u;
        unsigned y3 = (s_mask[a3] >> b3) & 1u;

        float s0 = sc.x, s1 = sc.y, s2 = sc.z, s3 = sc.w;

        float t0 = __builtin_amdgcn_exp2f(-fabsf(s0) * LOG2E);
        float t1 = __builtin_amdgcn_exp2f(-fabsf(s1) * LOG2E);
        float t2 = __builtin_amdgcn_exp2f(-fabsf(s2) * LOG2E);
        float t3 = __builtin_amdgcn_exp2f(-fabsf(s3) * LOG2E);

        acc += fmaxf(s0, 0.0f) - (y0 ? s0 : 0.0f) + LN2 * __builtin_amdgcn_logf(1.0f + t0);
        acc += fmaxf(s1, 0.0f) - (y1 ? s1 : 0.0f) + LN2 * __builtin_amdgcn_logf(1.0f + t1);
        acc += fmaxf(s2, 0.0f) - (y2 ? s2 : 0.0f) + LN2 * __builtin_amdgcn_logf(1.0f + t2);
        acc += fmaxf(s3, 0.0f) - (y3 ? s3 : 0.0f) + LN2 * __builtin_amdgcn_logf(1.0f + t3);
    }

    // scalar tail
    for (int e = (ngrp << 2) + gtid; e < n_edges; e += stride) {
        int n = edge_src[e], m = edge_dst[e];
        int a = (s_packed[n >> 3] >> ((n & 7) << 2)) & 0xF;
        int b = (s_packed[m >> 3] >> ((m & 7) << 2)) & 0xF;
        unsigned y = (s_mask[a] >> b) & 1u;
        float s = edge_scores[e];
        float t = __builtin_amdgcn_exp2f(-fabsf(s) * LOG2E);
        acc += fmaxf(s, 0.0f) - (y ? s : 0.0f) + LN2 * __builtin_amdgcn_logf(1.0f + t);
    }

    #pragma unroll
    for (int off = 32; off > 0; off >>= 1)
        acc += __shfl_down(acc, off, 64);

    const int wave = tid >> 6;
    const int lane = tid & 63;
    if (lane == 0) s_wsum[wave] = acc;
    __syncthreads();

    if (tid == 0) {
        float b = 0.0f;
        #pragma unroll
        for (int w = 0; w < EDGE_THREADS / 64; ++w) b += s_wsum[w];
        partial[blockIdx.x] = b;
    }
}

// ---------- fallback if ws too small / nodes too many ----------
__global__ __launch_bounds__(256) void edge_loss_fallback(
    const int*   __restrict__ node_classes,
    const float* __restrict__ edge_scores,
    const int*   __restrict__ edge_src,
    const int*   __restrict__ edge_dst,
    const float* __restrict__ adj,
    float*       __restrict__ partial,
    int n_edges)
{
    __shared__ unsigned s_mask[16];
    const int tid = threadIdx.x;
    if (tid < 12) {
        unsigned m = 0u;
        for (int j = 0; j < 12; ++j)
            if (adj[tid * 12 + j] > 0.5f) m |= (1u << j);
        s_mask[tid] = m;
    }
    __syncthreads();
    const int gtid   = blockIdx.x * 256 + tid;
    const int stride = gridDim.x * 256;
    float acc = 0.0f;
    for (int e = gtid; e < n_edges; e += stride) {
        int a = node_classes[edge_src[e]];
        int b = node_classes[edge_dst[e]];
        float y = (float)((s_mask[a] >> b) & 1u);
        float s = edge_scores[e];
        float t = __builtin_amdgcn_exp2f(-fabsf(s) * LOG2E);
        acc += fmaxf(s, 0.0f) - s * y + LN2 * __builtin_amdgcn_logf(1.0f + t);
    }
    #pragma unroll
    for (int off = 32; off > 0; off >>= 1)
        acc += __shfl_down(acc, off, 64);
    __shared__ float s_wsum[4];
    const int wave = tid >> 6, lane = tid & 63;
    if (lane == 0) s_wsum[wave] = acc;
    __syncthreads();
    if (tid == 0) {
        float b = 0.0f;
        for (int w = 0; w < 4; ++w) b += s_wsum[w];
        partial[blockIdx.x] = b;
    }
}

__global__ __launch_bounds__(256) void final_reduce(
    const float* __restrict__ partial,
    float*       __restrict__ out,
    int nblk, float inv_n)
{
    const int tid = threadIdx.x;
    double acc = 0.0;
    for (int i = tid; i < nblk; i += 256) acc += (double)partial[i];
    #pragma unroll
    for (int off = 32; off > 0; off >>= 1)
        acc += __shfl_down(acc, off, 64);
    __shared__ double s_wsum[4];
    const int wave = tid >> 6, lane = tid & 63;
    if (lane == 0) s_wsum[wave] = acc;
    __syncthreads();
    if (tid == 0) {
        double t = s_wsum[0] + s_wsum[1] + s_wsum[2] + s_wsum[3];
        out[0] = (float)(t * (double)inv_n);
    }
}

extern "C" void kernel_launch(void* const* d_in, const int* in_sizes, int n_in,
                              void* d_out, int out_size, void* d_ws, size_t ws_size,
                              hipStream_t stream) {
    const int*   node_classes = (const int*)  d_in[0];
    const float* edge_scores  = (const float*)d_in[1];
    const int*   edge_indices = (const int*)  d_in[2];
    const float* adj          = (const float*)d_in[3];

    const int n_nodes = in_sizes[0];
    const int n_edges = in_sizes[1];
    const int n_words = (n_nodes + 7) >> 3;

    const int* edge_src = edge_indices;
    const int* edge_dst = edge_indices + n_edges;

    char* ws = (char*)d_ws;
    float*    partial = (float*)   (ws + WS_PART_OFF);
    unsigned* packed  = (unsigned*)(ws + WS_PACK_OFF);
    float* out = (float*)d_out;

    const size_t needed = (size_t)WS_PACK_OFF + (size_t)n_words * 4u;

    if (ws_size >= needed && n_words <= PACK_WORDS_MAX) {
        int pack_blocks = (n_words + 255) / 256;
        pack_classes<<<pack_blocks, 256, 0, stream>>>(
            node_classes, packed, n_nodes, n_words);
        edge_loss_lds<<<EDGE_BLOCKS, EDGE_THREADS, 0, stream>>>(
            packed, edge_scores, edge_src, edge_dst, adj, partial,
            n_edges, n_words);
        final_reduce<<<1, 256, 0, stream>>>(partial, out, EDGE_BLOCKS,
                                            1.0f / (float)n_edges);
    } else {
        edge_loss_fallback<<<2048, 256, 0, stream>>>(
            node_classes, edge_scores, edge_src, edge_dst, adj, partial, n_edges);
        final_reduce<<<1, 256, 0, stream>>>(partial, out, 2048,
                                            1.0f / (float)n_edges);
    }
}

// Round 4
// 120.528 us; speedup vs baseline: 1.4452x; 1.0066x over previous
//
#include <hip/hip_runtime.h>

#define EDGE_BLOCKS  512
#define EDGE_THREADS 1024
#define PACK_WORDS_MAX 12512   // 50,048 B LDS table -> supports n_nodes <= 100,096

// ws layout (bytes):
//   [256, 256+EDGE_BLOCKS*4)    : per-block float partials
//   [8192, 8192+4*n_words)      : packed 4-bit node-class table
#define WS_PART_OFF    256
#define WS_PACK_OFF    8192

#define LOG2E 1.44269504088896f
#define LN2   0.69314718055995f

// ---------- kernel A: pack node classes to nibbles ----------
__global__ void pack_classes(const int* __restrict__ node_classes,
                             unsigned* __restrict__ packed,
                             int n_nodes, int n_words)
{
    int w = blockIdx.x * blockDim.x + threadIdx.x;
    if (w < n_words) {
        unsigned v = 0;
        int base = w << 3;
        #pragma unroll
        for (int j = 0; j < 8; ++j) {
            int n = base + j;
            unsigned c = (n < n_nodes) ? (unsigned)node_classes[n] : 0u;
            v |= (c & 0xFu) << (4 * j);
        }
        packed[w] = v;
    }
}

// ---------- kernel B: edge loss, LDS class table, pipelined ----------
__global__ __launch_bounds__(EDGE_THREADS, 8) void edge_loss_lds(
    const unsigned* __restrict__ packed_g,
    const float* __restrict__ edge_scores,
    const int*   __restrict__ edge_src,
    const int*   __restrict__ edge_dst,
    const float* __restrict__ adj,
    float*       __restrict__ partial,
    int n_edges, int n_words)
{
    __shared__ unsigned s_packed[PACK_WORDS_MAX]; // 50,048 B
    __shared__ unsigned s_mask[16];
    __shared__ float    s_wsum[EDGE_THREADS / 64];

    const int tid = threadIdx.x;

    if (tid < 16) {
        unsigned m = 0u;
        if (tid < 12) {
            #pragma unroll
            for (int j = 0; j < 12; ++j)
                if (adj[tid * 12 + j] > 0.5f) m |= (1u << j);
        }
        s_mask[tid] = m;
    }
    {
        int nv = n_words >> 2;
        const uint4* p4 = (const uint4*)packed_g;
        for (int i = tid; i < nv; i += EDGE_THREADS) {
            uint4 v = p4[i];
            s_packed[4*i+0] = v.x; s_packed[4*i+1] = v.y;
            s_packed[4*i+2] = v.z; s_packed[4*i+3] = v.w;
        }
        for (int i = (nv << 2) + tid; i < n_words; i += EDGE_THREADS)
            s_packed[i] = packed_g[i];
    }
    __syncthreads();

    const int gtid   = blockIdx.x * EDGE_THREADS + tid;
    const int stride = gridDim.x * EDGE_THREADS;
    const int ngrp   = n_edges >> 2;

    const int4*   srcv = (const int4*)  edge_src;
    const int4*   dstv = (const int4*)  edge_dst;
    const float4* scov = (const float4*)edge_scores;

    float acc_a = 0.0f;   // max(s,0) - y*s terms
    float acc_l = 0.0f;   // log2(1+exp2(-|s|*log2e)) terms (scale by LN2 at end)

    int g = gtid;
    if (g < ngrp) {
        // --- software pipeline: prefetch trip 0 ---
        int4   si = srcv[g];
        int4   di = dstv[g];
        float4 sc = scov[g];

        while (true) {
            const int gn = g + stride;
            int4 si_n, di_n; float4 sc_n;
            const bool more = (gn < ngrp);
            if (more) {              // issue next trip's loads before compute
                si_n = srcv[gn];
                di_n = dstv[gn];
                sc_n = scov[gn];
            }

            // nibble gathers (random LDS)
            unsigned wa0 = s_packed[si.x >> 3], wa1 = s_packed[si.y >> 3];
            unsigned wa2 = s_packed[si.z >> 3], wa3 = s_packed[si.w >> 3];
            unsigned wb0 = s_packed[di.x >> 3], wb1 = s_packed[di.y >> 3];
            unsigned wb2 = s_packed[di.z >> 3], wb3 = s_packed[di.w >> 3];

            int a0 = (wa0 >> ((si.x & 7) << 2)) & 0xF;
            int a1 = (wa1 >> ((si.y & 7) << 2)) & 0xF;
            int a2 = (wa2 >> ((si.z & 7) << 2)) & 0xF;
            int a3 = (wa3 >> ((si.w & 7) << 2)) & 0xF;
            int b0 = (wb0 >> ((di.x & 7) << 2)) & 0xF;
            int b1 = (wb1 >> ((di.y & 7) << 2)) & 0xF;
            int b2 = (wb2 >> ((di.z & 7) << 2)) & 0xF;
            int b3 = (wb3 >> ((di.w & 7) << 2)) & 0xF;

            unsigned y0 = (s_mask[a0] >> b0) & 1u;
            unsigned y1 = (s_mask[a1] >> b1) & 1u;
            unsigned y2 = (s_mask[a2] >> b2) & 1u;
            unsigned y3 = (s_mask[a3] >> b3) & 1u;

            float s0 = sc.x, s1 = sc.y, s2 = sc.z, s3 = sc.w;

            float t0 = __builtin_amdgcn_exp2f(-fabsf(s0) * LOG2E);
            float t1 = __builtin_amdgcn_exp2f(-fabsf(s1) * LOG2E);
            float t2 = __builtin_amdgcn_exp2f(-fabsf(s2) * LOG2E);
            float t3 = __builtin_amdgcn_exp2f(-fabsf(s3) * LOG2E);

            acc_a += fmaxf(s0, 0.0f) - (y0 ? s0 : 0.0f);
            acc_a += fmaxf(s1, 0.0f) - (y1 ? s1 : 0.0f);
            acc_a += fmaxf(s2, 0.0f) - (y2 ? s2 : 0.0f);
            acc_a += fmaxf(s3, 0.0f) - (y3 ? s3 : 0.0f);

            acc_l += __builtin_amdgcn_logf(1.0f + t0);
            acc_l += __builtin_amdgcn_logf(1.0f + t1);
            acc_l += __builtin_amdgcn_logf(1.0f + t2);
            acc_l += __builtin_amdgcn_logf(1.0f + t3);

            if (!more) break;
            si = si_n; di = di_n; sc = sc_n; g = gn;
        }
    }

    // scalar tail (n_edges not divisible by 4)
    for (int e = (ngrp << 2) + gtid; e < n_edges; e += stride) {
        int n = edge_src[e], m = edge_dst[e];
        int a = (s_packed[n >> 3] >> ((n & 7) << 2)) & 0xF;
        int b = (s_packed[m >> 3] >> ((m & 7) << 2)) & 0xF;
        unsigned y = (s_mask[a] >> b) & 1u;
        float s = edge_scores[e];
        float t = __builtin_amdgcn_exp2f(-fabsf(s) * LOG2E);
        acc_a += fmaxf(s, 0.0f) - (y ? s : 0.0f);
        acc_l += __builtin_amdgcn_logf(1.0f + t);
    }

    float acc = fmaf(LN2, acc_l, acc_a);

    #pragma unroll
    for (int off = 32; off > 0; off >>= 1)
        acc += __shfl_down(acc, off, 64);

    const int wave = tid >> 6;
    const int lane = tid & 63;
    if (lane == 0) s_wsum[wave] = acc;
    __syncthreads();

    if (tid == 0) {
        float b = 0.0f;
        #pragma unroll
        for (int w = 0; w < EDGE_THREADS / 64; ++w) b += s_wsum[w];
        partial[blockIdx.x] = b;
    }
}

// ---------- fallback if ws too small / nodes too many ----------
__global__ __launch_bounds__(256) void edge_loss_fallback(
    const int*   __restrict__ node_classes,
    const float* __restrict__ edge_scores,
    const int*   __restrict__ edge_src,
    const int*   __restrict__ edge_dst,
    const float* __restrict__ adj,
    float*       __restrict__ partial,
    int n_edges)
{
    __shared__ unsigned s_mask[16];
    const int tid = threadIdx.x;
    if (tid < 12) {
        unsigned m = 0u;
        for (int j = 0; j < 12; ++j)
            if (adj[tid * 12 + j] > 0.5f) m |= (1u << j);
        s_mask[tid] = m;
    }
    __syncthreads();
    const int gtid   = blockIdx.x * 256 + tid;
    const int stride = gridDim.x * 256;
    float acc = 0.0f;
    for (int e = gtid; e < n_edges; e += stride) {
        int a = node_classes[edge_src[e]];
        int b = node_classes[edge_dst[e]];
        float y = (float)((s_mask[a] >> b) & 1u);
        float s = edge_scores[e];
        float t = __builtin_amdgcn_exp2f(-fabsf(s) * LOG2E);
        acc += fmaxf(s, 0.0f) - s * y + LN2 * __builtin_amdgcn_logf(1.0f + t);
    }
    #pragma unroll
    for (int off = 32; off > 0; off >>= 1)
        acc += __shfl_down(acc, off, 64);
    __shared__ float s_wsum[4];
    const int wave = tid >> 6, lane = tid & 63;
    if (lane == 0) s_wsum[wave] = acc;
    __syncthreads();
    if (tid == 0) {
        float b = 0.0f;
        for (int w = 0; w < 4; ++w) b += s_wsum[w];
        partial[blockIdx.x] = b;
    }
}

__global__ __launch_bounds__(256) void final_reduce(
    const float* __restrict__ partial,
    float*       __restrict__ out,
    int nblk, float inv_n)
{
    const int tid = threadIdx.x;
    double acc = 0.0;
    for (int i = tid; i < nblk; i += 256) acc += (double)partial[i];
    #pragma unroll
    for (int off = 32; off > 0; off >>= 1)
        acc += __shfl_down(acc, off, 64);
    __shared__ double s_wsum[4];
    const int wave = tid >> 6, lane = tid & 63;
    if (lane == 0) s_wsum[wave] = acc;
    __syncthreads();
    if (tid == 0) {
        double t = s_wsum[0] + s_wsum[1] + s_wsum[2] + s_wsum[3];
        out[0] = (float)(t * (double)inv_n);
    }
}

extern "C" void kernel_launch(void* const* d_in, const int* in_sizes, int n_in,
                              void* d_out, int out_size, void* d_ws, size_t ws_size,
                              hipStream_t stream) {
    const int*   node_classes = (const int*)  d_in[0];
    const float* edge_scores  = (const float*)d_in[1];
    const int*   edge_indices = (const int*)  d_in[2];
    const float* adj          = (const float*)d_in[3];

    const int n_nodes = in_sizes[0];
    const int n_edges = in_sizes[1];
    const int n_words = (n_nodes + 7) >> 3;

    const int* edge_src = edge_indices;
    const int* edge_dst = edge_indices + n_edges;

    char* ws = (char*)d_ws;
    float*    partial = (float*)   (ws + WS_PART_OFF);
    unsigned* packed  = (unsigned*)(ws + WS_PACK_OFF);
    float* out = (float*)d_out;

    const size_t needed = (size_t)WS_PACK_OFF + (size_t)n_words * 4u;

    if (ws_size >= needed && n_words <= PACK_WORDS_MAX) {
        int pack_blocks = (n_words + 255) / 256;
        pack_classes<<<pack_blocks, 256, 0, stream>>>(
            node_classes, packed, n_nodes, n_words);
        edge_loss_lds<<<EDGE_BLOCKS, EDGE_THREADS, 0, stream>>>(
            packed, edge_scores, edge_src, edge_dst, adj, partial,
            n_edges, n_words);
        final_reduce<<<1, 256, 0, stream>>>(partial, out, EDGE_BLOCKS,
                                            1.0f / (float)n_edges);
    } else {
        edge_loss_fallback<<<2048, 256, 0, stream>>>(
            node_classes, edge_scores, edge_src, edge_dst, adj, partial, n_edges);
        final_reduce<<<1, 256, 0, stream>>>(partial, out, 2048,
                                            1.0f / (float)n_edges);
    }
}